// Round 3
// baseline (110.971 us; speedup 1.0000x reference)
//
#include <hip/hip_runtime.h>

// SampledSoftmaxLoss: N=51200 rows, D=64, K=100 negatives, V=100001 items.
// loss = sum_n w_n * (logsumexp(logits_n) - pos_logit_n) / sum_n w_n
// logits = cos_sim(vo_n, item_idx) / 0.05
//
// r9: D-SPLIT TABLE for L2 residency. Evidence r5/r7/r8: three structurally
// different kernels all pinned at 2.2-2.6 TB/s L2-miss BW with FETCH=152MB,
// dur == FETCH/BW -> random-miss path saturates ~2.4 TB/s; fetch dominated
// by table capacity misses (6.4MB fp8 table vs 4MB L2/XCD -> 38% miss of
// 331MB demand = 126MB). Fix: split table BY DIMENSION into tabA (dims
// 0-31, 3.2MB) + tabB (dims 32-63, 3.2MB); block runs phase A (partial
// dots, parked in LDS) over its 25 rows, then phase B (complete + softmax).
// Chip-wide, each phase's working set is 3.2MB < 4MB L2 -> gathers become
// L2 hits; misses ~= compulsory per-XCD fills (~51MB total). negi re-read
// in phase B as NT *streaming* bytes (cheap), NT so streams don't evict
// the table. Numerics identical (same fp8 values; fp32 dot = two fp32
// partial adds). LDS ~19KB, VGPR<=64 -> 8 blocks/CU, 32 waves/CU.

#define D_DIM 64
#define K_NEG 100
#define INV_TEMP 20.0f
#define MAX_LOGIT 20.0f
#define LOG2E 1.4426950408889634f
#define LN2 0.6931471805599453f
#define MAXL2 28.853900817779268f   // MAX_LOGIT * LOG2E

#define NBLK_NORM 1024
#define MAXR 25      // rows per block; grid = ceil(N/MAXR) = 2048 @ N=51200
#define NSLOT 128    // slots per row (101 used)
#define PSTRIDE 104  // s_part row stride in floats (101 used)

typedef float fv2 __attribute__((ext_vector_type(2)));

__device__ __forceinline__ void gload_lds16(const void* g, void* l) {
  __builtin_amdgcn_global_load_lds(
      (const __attribute__((address_space(1))) unsigned int*)g,
      (__attribute__((address_space(3))) unsigned int*)l, 16, 0, 0);
}

// ------- Pass 1: normalize item table -> fp8 e4m3, split by dims -------
__global__ __launch_bounds__(256) void normalize_kernel(
    const float* __restrict__ items, unsigned int* __restrict__ tabA,
    unsigned int* __restrict__ tabB, int V) {
  const int lane = threadIdx.x & 63;
  const int wid  = threadIdx.x >> 6;
  const int g = lane >> 4, q = lane & 15;   // q covers dims 4q..4q+3
  const int waveId = blockIdx.x * 4 + wid;
  const int nWaves = gridDim.x * 4;
  for (int base = waveId * 4; base < V; base += nWaves * 4) {
    const int r = base + g;
    const bool act = (r < V);
    float4 x = make_float4(0.f, 0.f, 0.f, 0.f);
    if (act) x = *reinterpret_cast<const float4*>(items + (size_t)r * D_DIM + q * 4);
    float ss = x.x * x.x + x.y * x.y + x.z * x.z + x.w * x.w;
    ss += __shfl_xor(ss, 1);
    ss += __shfl_xor(ss, 2);
    ss += __shfl_xor(ss, 4);
    ss += __shfl_xor(ss, 8);
    const float inv = 1.0f / fmaxf(sqrtf(ss), 1e-12f);
    if (act) {
      int u = 0;
      u = __builtin_amdgcn_cvt_pk_fp8_f32(x.x * inv, x.y * inv, u, false);
      u = __builtin_amdgcn_cvt_pk_fp8_f32(x.z * inv, x.w * inv, u, true);
      unsigned int* t = (q < 8) ? (tabA + (size_t)r * 8 + q)
                                : (tabB + (size_t)r * 8 + (q - 8));
      *t = (unsigned int)u;
    }
  }
}

// ------- Pass 2: main loss, two dimension-phases per block -------
// Block owns rows r0 + k*G, k in [0,nr), nr<=MAXR. Per phase: slot s=tid>>1
// (0..127; 0=positive, 1..100=negs), half h=tid&1 covers 16 of the phase's
// 32 dims. Staging: wave w issues one global_load_lds (16B/lane) for slots
// 32w..32w+31; LDS dest is linear in tid (= slot*2+h), matching lane*16.
__global__ __launch_bounds__(256, 8) void loss_kernel(
    const float* __restrict__ oe,       // [N,64]
    const int*   __restrict__ tgt,      // [N]
    const unsigned int* __restrict__ tabA, // [V][8] dwords fp8 (dims 0-31)
    const unsigned int* __restrict__ tabB, // [V][8] dwords fp8 (dims 32-63)
    const float* __restrict__ wgt,      // [N]
    const int*   __restrict__ negi,     // [N,100]
    const int*   __restrict__ alti,     // [N,100]
    float2*      __restrict__ partials, // [gridDim.x]
    int N) {
  __shared__ uint4 s_items[2][NSLOT * 2];   // 8 KB  (dbuf, 32B/slot)
  __shared__ float s_q[2][32];              // 256 B (dbuf, phase q chunk)
  __shared__ float s_part[MAXR][PSTRIDE];   // 10.4 KB partial dots (phase A)
  __shared__ float s_ss[MAXR];              // per-row partial |q|^2
  __shared__ float s_red[2][4];

  const int tid  = threadIdx.x;
  const int lane = tid & 63;
  const int wid  = tid >> 6;
  const int s    = tid >> 1;
  const int h    = tid & 1;
  const int j    = s - 1;
  const bool sval = (s <= K_NEG);
  const bool nval = sval && (s >= 1);
  const int G  = gridDim.x;
  const int r0 = blockIdx.x;
  const int nr = (N - r0 + G - 1) / G;

  float num = 0.f, den = 0.f;

  uint4* const dst0 = &s_items[0][wid * 64];   // wave-uniform LDS bases
  uint4* const dst1 = &s_items[1][wid * 64];

  auto run_phase = [&](const unsigned int* __restrict__ TAB, int P, bool FIN) {
    // resolve idx + issue this wave's gathers + q chunk for rowS -> buf nb
    auto STAGE = [&](int rowS, int nb, int rawneg, int tS) {
      int v = (s == 0) ? tS : rawneg;
      if (nval && v == tS) v = alti[(size_t)rowS * K_NEG + j];  // rare
      if (sval) gload_lds16(TAB + (size_t)v * 8 + h * 4, nb ? dst1 : dst0);
      if (wid == 3 && lane < 8)
        gload_lds16(oe + (size_t)rowS * D_DIM + P * 32 + lane * 4,
                    nb ? &s_q[1][0] : &s_q[0][0]);
    };

    int rawneg = 0, tS = 0;
    // prologue: stage row k=0, preload idx for k=1
    if (nval) rawneg = __builtin_nontemporal_load(negi + (size_t)r0 * K_NEG + j);
    tS = tgt[r0];
    STAGE(r0, 0, rawneg, tS);
    if (nr > 1) {
      const int r1 = r0 + G;
      rawneg = nval ? __builtin_nontemporal_load(negi + (size_t)r1 * K_NEG + j) : 0;
      tS = tgt[r1];
    }
    __syncthreads();

    int buf = 0;
    for (int k = 0; k < nr; ++k) {
      const int r = r0 + k * G;
      if (k + 1 < nr) STAGE(r0 + (k + 1) * G, buf ^ 1, rawneg, tS);
      if (k + 2 < nr) {
        const int r2 = r0 + (k + 2) * G;
        rawneg = nval ? __builtin_nontemporal_load(negi + (size_t)r2 * K_NEG + j) : 0;
        tS = tgt[r2];
      }
      const float w = FIN ? wgt[r] : 0.f;   // uniform scalar load

      // ---- compute row k from buf ----
      const float4* qp = reinterpret_cast<const float4*>(&s_q[buf][h * 16]);
      const float4 x0 = qp[0], x1 = qp[1], x2 = qp[2], x3 = qp[3];
      const fv2 qa0 = {x0.x, x0.y}, qa1 = {x0.z, x0.w};
      const fv2 qa2 = {x1.x, x1.y}, qa3 = {x1.z, x1.w};
      const fv2 qa4 = {x2.x, x2.y}, qa5 = {x2.z, x2.w};
      const fv2 qa6 = {x3.x, x3.y}, qa7 = {x3.z, x3.w};

      fv2 ss2 = qa0 * qa0;
      ss2 += qa1 * qa1;
      ss2 += qa2 * qa2;
      ss2 += qa3 * qa3;
      ss2 += qa4 * qa4;
      ss2 += qa5 * qa5;
      ss2 += qa6 * qa6;
      ss2 += qa7 * qa7;
      float ssh = ss2[0] + ss2[1];
      ssh += __shfl_xor(ssh, 1);            // 32-dim phase |q|^2 partial

      const uint4 rv = s_items[buf][tid];   // lane-linear ds_read_b128
      fv2 acc;
      acc  = qa0 * __builtin_amdgcn_cvt_pk_f32_fp8((int)rv.x, false);
      acc += qa1 * __builtin_amdgcn_cvt_pk_f32_fp8((int)rv.x, true);
      acc += qa2 * __builtin_amdgcn_cvt_pk_f32_fp8((int)rv.y, false);
      acc += qa3 * __builtin_amdgcn_cvt_pk_f32_fp8((int)rv.y, true);
      acc += qa4 * __builtin_amdgcn_cvt_pk_f32_fp8((int)rv.z, false);
      acc += qa5 * __builtin_amdgcn_cvt_pk_f32_fp8((int)rv.z, true);
      acc += qa6 * __builtin_amdgcn_cvt_pk_f32_fp8((int)rv.w, false);
      acc += qa7 * __builtin_amdgcn_cvt_pk_f32_fp8((int)rv.w, true);
      float d = acc[0] + acc[1];
      d += __shfl_xor(d, 1);                // 32-dim phase dot for slot s

      float pos = 0.f;
      if (!FIN) {
        if (h == 0 && sval) s_part[k][s] = d;
        if (tid == 0) s_ss[k] = ssh;
      } else {
        const float sstot = ssh + s_ss[k];
        const float sc = INV_TEMP / fmaxf(sqrtf(sstot), 1e-12f);
        float tot = 0.f;
        if (sval) tot = s_part[k][s] + d;
        float e = 0.f;
        if (h == 0 && sval) e = exp2f(fmaf(tot, sc * LOG2E, -MAXL2));
        e += __shfl_xor(e, 1);
        e += __shfl_xor(e, 2);
        e += __shfl_xor(e, 4);
        e += __shfl_xor(e, 8);
        e += __shfl_xor(e, 16);
        e += __shfl_xor(e, 32);
        if (lane == 0) s_red[buf][wid] = e;
        if (tid == 0) pos = tot * sc;       // slot 0 = positive logit
      }

      // one barrier: s_red visible, next buf's gathers drained (vmcnt(0))
      __syncthreads();

      if (FIN && tid == 0) {
        const float S = s_red[buf][0] + s_red[buf][1] + s_red[buf][2] + s_red[buf][3];
        const float lse = log2f(S) * LN2 + MAX_LOGIT;
        const float loss = lse - pos;
        if (w > 0.f) {
          num += loss * w;
          den += w;
        }
      }
      buf ^= 1;
    }
  };

  run_phase(tabA, 0, false);   // dims 0-31: partial dots -> s_part
  run_phase(tabB, 1, true);    // dims 32-63: complete + softmax + loss

  if (tid == 0) partials[blockIdx.x] = make_float2(num, den);
}

// ---------------- Pass 3: final reduce ----------------
__global__ __launch_bounds__(256) void finish_kernel(
    const float2* __restrict__ partials, int nblk, float* __restrict__ out) {
  float num = 0.f, den = 0.f;
  for (int i = threadIdx.x; i < nblk; i += 256) {
    const float2 p = partials[i];
    num += p.x;
    den += p.y;
  }
#pragma unroll
  for (int m = 1; m < 64; m <<= 1) {
    num += __shfl_xor(num, m);
    den += __shfl_xor(den, m);
  }
  __shared__ float2 red[4];
  const int wid = threadIdx.x >> 6;
  const int lane = threadIdx.x & 63;
  if (lane == 0) red[wid] = make_float2(num, den);
  __syncthreads();
  if (threadIdx.x == 0) {
    float n = 0.f, d = 0.f;
#pragma unroll
    for (int i = 0; i < 4; ++i) { n += red[i].x; d += red[i].y; }
    out[0] = n / d;
  }
}

extern "C" void kernel_launch(void* const* d_in, const int* in_sizes, int n_in,
                              void* d_out, int out_size, void* d_ws, size_t ws_size,
                              hipStream_t stream) {
  const float* oe    = (const float*)d_in[0];  // output_embeddings [B,S,64]
  const int*   tgt   = (const int*)  d_in[1];  // target_ids [B,S]
  const float* items = (const float*)d_in[2];  // all_item_embeddings [V,64]
  const float* wgt   = (const float*)d_in[3];  // supervision_weights [B,S]
  const int*   negi  = (const int*)  d_in[4];  // neg_indices [N,100]
  const int*   alti  = (const int*)  d_in[5];  // alt_neg_indices [N,100]

  const int N = in_sizes[0] / D_DIM;  // 51200
  const int V = in_sizes[2] / D_DIM;  // 100001
  const int G = (N + MAXR - 1) / MAXR;  // 2048 @ N=51200

  unsigned int* tabA = (unsigned int*)d_ws;        // V*32 B (dims 0-31)
  unsigned int* tabB = tabA + (size_t)V * 8;       // V*32 B (dims 32-63)
  size_t off = ((size_t)V * 16 * sizeof(unsigned int) + 255) & ~(size_t)255;
  float2* partials = (float2*)((char*)d_ws + off); // G float2

  normalize_kernel<<<NBLK_NORM, 256, 0, stream>>>(items, tabA, tabB, V);
  loss_kernel<<<G, 256, 0, stream>>>(oe, tgt, tabA, tabB, wgt, negi, alti,
                                     partials, N);
  finish_kernel<<<1, 256, 0, stream>>>(partials, G, (float*)d_out);
}

// Round 4
// 107.886 us; speedup vs baseline: 1.0286x; 1.0286x over previous
//
#include <hip/hip_runtime.h>

// SampledSoftmaxLoss: N=51200 rows, D=64, K=100 negatives, V=100001 items.
// loss = sum_n w_n * (logsumexp(logits_n) - pos_logit_n) / sum_n w_n
// logits = cos_sim(vo_n, item_idx) / 0.05
//
// r10: WAVE-PRIVATE + D-SPLIT. History:
//  r5 (wave-private, full 6.4MB fp8 table): 59.7us, FETCH 152MB @2.6TB/s
//     -> HBM random-64B-line misses were the limiter (6.4MB > 4MB L2/XCD).
//  r9 (block-coop D-split, barriers): FETCH 68MB (= streams; table gathers
//     all cache hits -> capacity theory CONFIRMED) but 104us: __syncthreads
//     emits s_waitcnt vmcnt(0), draining the NEXT row's global_load_lds
//     issued just before it -> pipeline depth 0, latency exposed per row.
// Fix: r5's barrier-free wave-private execution + r9's dimension-split
// tables. Wave owns <=7 rows. Sweep A: 32-dim partial dots from tabA
// (3.2MB, L2-resident chip-wide during the sweep), parked in a wave-
// private LDS slab (no barrier: same wave writes & reads). Sweep B:
// re-resolve indices (NT stream re-read), gather tabB, complete dots +
// online softmax + loss. Compiler inserts counted vmcnt (no vmcnt(0)
// drains). LDS 11.7KB/block, VGPR target <=72 -> full residency at 2048
// blocks. Expected: ~40-50us, FETCH ~70-90MB, VALUBusy >=70%.

#define D_DIM 64
#define K_NEG 100
#define INV_TEMP 20.0f
#define MAX_LOGIT 20.0f
#define LOG2E 1.4426950408889634f
#define LN2 0.6931471805599453f
#define MAXL2 28.853900817779268f   // MAX_LOGIT * LOG2E

#define NBLK_MAIN 2048
#define NBLK_NORM 1024
#define NT 7      // ceil(101/16) tiles of 16 slots
#define MAXK 7    // rows per wave: ceil(51200 / 8192)
#define PSTRIDE 104  // LDS floats per row: 101 partials + [101]=ssA + pad

typedef float fv2 __attribute__((ext_vector_type(2)));

// ------- Pass 1: normalize item table -> fp8 e4m3, split by dims -------
// tabA[v] = dims 0-31 (32B, 8 dwords), tabB[v] = dims 32-63.
__global__ __launch_bounds__(256) void normalize_kernel(
    const float* __restrict__ items, unsigned int* __restrict__ tabA,
    unsigned int* __restrict__ tabB, int V) {
  const int lane = threadIdx.x & 63;
  const int wid  = threadIdx.x >> 6;
  const int g = lane >> 4, q = lane & 15;   // q covers dims 4q..4q+3
  const int waveId = blockIdx.x * 4 + wid;
  const int nWaves = gridDim.x * 4;
  for (int base = waveId * 4; base < V; base += nWaves * 4) {
    const int r = base + g;
    const bool act = (r < V);
    float4 x = make_float4(0.f, 0.f, 0.f, 0.f);
    if (act) x = *reinterpret_cast<const float4*>(items + (size_t)r * D_DIM + q * 4);
    float ss = x.x * x.x + x.y * x.y + x.z * x.z + x.w * x.w;
    ss += __shfl_xor(ss, 1);
    ss += __shfl_xor(ss, 2);
    ss += __shfl_xor(ss, 4);
    ss += __shfl_xor(ss, 8);
    const float inv = 1.0f / fmaxf(sqrtf(ss), 1e-12f);
    if (act) {
      int u = 0;
      u = __builtin_amdgcn_cvt_pk_fp8_f32(x.x * inv, x.y * inv, u, false);
      u = __builtin_amdgcn_cvt_pk_fp8_f32(x.z * inv, x.w * inv, u, true);
      unsigned int* t = (q < 8) ? (tabA + (size_t)r * 8 + q)
                                : (tabB + (size_t)r * 8 + (q - 8));
      *t = (unsigned int)u;
    }
  }
}

// ------- Pass 2: main loss (wave-private, two dimension-sweeps) -------
// One wave per row-stream (16 groups x 4 lanes; group g owns slot j=16t+g,
// lane q owns 8 dims of the 32-dim phase window). Per phase: uint2 gather
// (8B/lane) per tile. Sweep A parks per-slot 32-dim partial dots + ssA in
// the wave's private LDS slab; sweep B completes and does the softmax.
__global__ __launch_bounds__(256) void loss_kernel(
    const float* __restrict__ oe,       // [N,64]
    const int*   __restrict__ tgt,      // [N]
    const unsigned int* __restrict__ tabA, // [V][8] dwords fp8 (dims 0-31)
    const unsigned int* __restrict__ tabB, // [V][8] dwords fp8 (dims 32-63)
    const float* __restrict__ wgt,      // [N]
    const int*   __restrict__ negi,     // [N,100]
    const int*   __restrict__ alti,     // [N,100]
    float2*      __restrict__ partials, // [gridDim.x]
    int N) {
  __shared__ float s_part[4][MAXK][PSTRIDE];  // 11648 B, wave-private slabs
  __shared__ float2 s_red[4];

  const int lane = threadIdx.x & 63;
  const int wid  = threadIdx.x >> 6;
  const int g = lane >> 2, q = lane & 3;
  const int waveId = blockIdx.x * 4 + wid;
  const int nWaves = gridDim.x * 4;

  float num = 0.f, den = 0.f;

  // load raw neg indices for this lane's 7 slots of a row
  auto LOADN = [&](int row, int* nj) {
    const int* nr = negi + (size_t)row * K_NEG;
    nj[0] = (g >= 1) ? __builtin_nontemporal_load(nr + g - 1) : 0;
    nj[1] = __builtin_nontemporal_load(nr + 16 + g - 1);
    nj[2] = __builtin_nontemporal_load(nr + 32 + g - 1);
    nj[3] = __builtin_nontemporal_load(nr + 48 + g - 1);
    nj[4] = __builtin_nontemporal_load(nr + 64 + g - 1);
    nj[5] = __builtin_nontemporal_load(nr + 80 + g - 1);
    nj[6] = (g <= 4) ? __builtin_nontemporal_load(nr + 96 + g - 1) : 0;
  };

  // resolve collisions -> id[7]
  auto RESOLVE = [&](const int* nj, int t_r, int row, int* id) {
    const int* ar = alti + (size_t)row * K_NEG;
    int v0 = (g == 0) ? t_r : nj[0];
    if (g >= 1 && v0 == t_r) v0 = ar[g - 1];        // rare, execz-skipped
    id[0] = v0;
    int v1 = nj[1]; if (v1 == t_r) v1 = ar[16 + g - 1]; id[1] = v1;
    int v2 = nj[2]; if (v2 == t_r) v2 = ar[32 + g - 1]; id[2] = v2;
    int v3 = nj[3]; if (v3 == t_r) v3 = ar[48 + g - 1]; id[3] = v3;
    int v4 = nj[4]; if (v4 == t_r) v4 = ar[64 + g - 1]; id[4] = v4;
    int v5 = nj[5]; if (v5 == t_r) v5 = ar[80 + g - 1]; id[5] = v5;
    int v6 = 0;
    if (g <= 4) { v6 = nj[6]; if (v6 == t_r) v6 = ar[96 + g - 1]; }
    id[6] = v6;
  };

  // ---------------- Sweep A: dims 0-31 -> partials in LDS ----------------
  {
    int row = waveId, k = 0;
    int t_r = 0, nj[NT];
    if (row < N) { t_r = tgt[row]; LOADN(row, nj); }
    while (row < N && k < MAXK) {
      const int nxt = row + nWaves;
      int id[NT];
      RESOLVE(nj, t_r, row, id);
      uint2 rb[NT];
#pragma unroll
      for (int t = 0; t < NT; ++t)
        rb[t] = *reinterpret_cast<const uint2*>(tabA + (size_t)id[t] * 8 + q * 2);
      if (nxt < N) { t_r = tgt[nxt]; LOADN(nxt, nj); }  // prefetch next idx

      // q-frag: dims q*8 .. q*8+7
      const float* orow = oe + (size_t)row * D_DIM + q * 8;
      const float4 x0 = *reinterpret_cast<const float4*>(orow + 0);
      const float4 x1 = *reinterpret_cast<const float4*>(orow + 4);
      const fv2 qa0 = {x0.x, x0.y}, qa1 = {x0.z, x0.w};
      const fv2 qa2 = {x1.x, x1.y}, qa3 = {x1.z, x1.w};

      fv2 ss2 = qa0 * qa0;
      ss2 += qa1 * qa1;
      ss2 += qa2 * qa2;
      ss2 += qa3 * qa3;
      float ss = ss2[0] + ss2[1];
      ss += __shfl_xor(ss, 1);
      ss += __shfl_xor(ss, 2);             // 32-dim |q|^2 partial
      if (lane == 0) s_part[wid][k][101] = ss;

#pragma unroll
      for (int t = 0; t < NT; ++t) {
        const uint2 r2 = rb[t];
        fv2 acc;
        acc  = qa0 * __builtin_amdgcn_cvt_pk_f32_fp8((int)r2.x, false);
        acc += qa1 * __builtin_amdgcn_cvt_pk_f32_fp8((int)r2.x, true);
        acc += qa2 * __builtin_amdgcn_cvt_pk_f32_fp8((int)r2.y, false);
        acc += qa3 * __builtin_amdgcn_cvt_pk_f32_fp8((int)r2.y, true);
        float d = acc[0] + acc[1];
        d += __shfl_xor(d, 1);
        d += __shfl_xor(d, 2);             // 32-dim partial dot for slot j
        const int j = t * 16 + g;
        if (q == 0 && j <= K_NEG) s_part[wid][k][j] = d;
      }
      row = nxt; ++k;
    }
  }

  // no barrier: sweep B reads only this wave's own slab (lgkmcnt suffices)

  // ---------------- Sweep B: dims 32-63 -> complete + softmax ----------------
  {
    int row = waveId, k = 0;
    int t_r = 0, nj[NT];
    float w = 0.f;
    if (row < N) { t_r = tgt[row]; w = wgt[row]; LOADN(row, nj); }
    while (row < N && k < MAXK) {
      const int nxt = row + nWaves;
      int id[NT];
      RESOLVE(nj, t_r, row, id);
      uint2 rb[NT];
#pragma unroll
      for (int t = 0; t < NT; ++t)
        rb[t] = *reinterpret_cast<const uint2*>(tabB + (size_t)id[t] * 8 + q * 2);
      float p_w = 0.f;
      if (nxt < N) { t_r = tgt[nxt]; p_w = wgt[nxt]; LOADN(nxt, nj); }

      // q-frag: dims 32 + q*8 ..
      const float* orow = oe + (size_t)row * D_DIM + 32 + q * 8;
      const float4 x0 = *reinterpret_cast<const float4*>(orow + 0);
      const float4 x1 = *reinterpret_cast<const float4*>(orow + 4);
      const fv2 qa0 = {x0.x, x0.y}, qa1 = {x0.z, x0.w};
      const fv2 qa2 = {x1.x, x1.y}, qa3 = {x1.z, x1.w};

      fv2 ss2 = qa0 * qa0;
      ss2 += qa1 * qa1;
      ss2 += qa2 * qa2;
      ss2 += qa3 * qa3;
      float ss = ss2[0] + ss2[1];
      ss += __shfl_xor(ss, 1);
      ss += __shfl_xor(ss, 2);
      const float sstot = ss + s_part[wid][k][101];   // broadcast read
      const float scale = INV_TEMP / fmaxf(sqrtf(sstot), 1e-12f);
      const float sc2 = scale * LOG2E;

      float sacc = 0.f, pos = 0.f;
#pragma unroll
      for (int t = 0; t < NT; ++t) {
        const uint2 r2 = rb[t];
        fv2 acc;
        acc  = qa0 * __builtin_amdgcn_cvt_pk_f32_fp8((int)r2.x, false);
        acc += qa1 * __builtin_amdgcn_cvt_pk_f32_fp8((int)r2.x, true);
        acc += qa2 * __builtin_amdgcn_cvt_pk_f32_fp8((int)r2.y, false);
        acc += qa3 * __builtin_amdgcn_cvt_pk_f32_fp8((int)r2.y, true);
        float d = acc[0] + acc[1];
        d += __shfl_xor(d, 1);
        d += __shfl_xor(d, 2);
        const int j = t * 16 + g;
        if (q == 0 && j <= K_NEG) {
          const float tot = d + s_part[wid][k][j];
          sacc += exp2f(fmaf(tot, sc2, -MAXL2));
          if (j == 0) pos = tot * scale;   // lane 0 only (g=0,q=0,t=0)
        }
      }
      sacc += __shfl_xor(sacc, 4);
      sacc += __shfl_xor(sacc, 8);
      sacc += __shfl_xor(sacc, 16);
      sacc += __shfl_xor(sacc, 32);
      if (lane == 0) {
        const float lse = log2f(sacc) * LN2 + MAX_LOGIT;
        const float loss = lse - pos;
        if (w > 0.f) {
          num += loss * w;
          den += w;
        }
      }
      w = p_w;
      row = nxt; ++k;
    }
  }

  if (lane == 0) s_red[wid] = make_float2(num, den);
  __syncthreads();
  if (threadIdx.x == 0) {
    float n = 0.f, d = 0.f;
#pragma unroll
    for (int i = 0; i < 4; ++i) { n += s_red[i].x; d += s_red[i].y; }
    partials[blockIdx.x] = make_float2(n, d);
  }
}

// ---------------- Pass 3: final reduce ----------------
__global__ __launch_bounds__(256) void finish_kernel(
    const float2* __restrict__ partials, int nblk, float* __restrict__ out) {
  float num = 0.f, den = 0.f;
  for (int i = threadIdx.x; i < nblk; i += 256) {
    const float2 p = partials[i];
    num += p.x;
    den += p.y;
  }
#pragma unroll
  for (int m = 1; m < 64; m <<= 1) {
    num += __shfl_xor(num, m);
    den += __shfl_xor(den, m);
  }
  __shared__ float2 red[4];
  const int wid = threadIdx.x >> 6;
  const int lane = threadIdx.x & 63;
  if (lane == 0) red[wid] = make_float2(num, den);
  __syncthreads();
  if (threadIdx.x == 0) {
    float n = 0.f, d = 0.f;
#pragma unroll
    for (int i = 0; i < 4; ++i) { n += red[i].x; d += red[i].y; }
    out[0] = n / d;
  }
}

extern "C" void kernel_launch(void* const* d_in, const int* in_sizes, int n_in,
                              void* d_out, int out_size, void* d_ws, size_t ws_size,
                              hipStream_t stream) {
  const float* oe    = (const float*)d_in[0];  // output_embeddings [B,S,64]
  const int*   tgt   = (const int*)  d_in[1];  // target_ids [B,S]
  const float* items = (const float*)d_in[2];  // all_item_embeddings [V,64]
  const float* wgt   = (const float*)d_in[3];  // supervision_weights [B,S]
  const int*   negi  = (const int*)  d_in[4];  // neg_indices [N,100]
  const int*   alti  = (const int*)  d_in[5];  // alt_neg_indices [N,100]

  const int N = in_sizes[0] / D_DIM;  // 51200
  const int V = in_sizes[2] / D_DIM;  // 100001

  unsigned int* tabA = (unsigned int*)d_ws;        // V*32 B (dims 0-31)
  unsigned int* tabB = tabA + (size_t)V * 8;       // V*32 B (dims 32-63)
  size_t off = ((size_t)V * 16 * sizeof(unsigned int) + 255) & ~(size_t)255;
  float2* partials = (float2*)((char*)d_ws + off); // NBLK_MAIN float2

  normalize_kernel<<<NBLK_NORM, 256, 0, stream>>>(items, tabA, tabB, V);
  loss_kernel<<<NBLK_MAIN, 256, 0, stream>>>(oe, tgt, tabA, tabB, wgt, negi,
                                             alti, partials, N);
  finish_kernel<<<1, 256, 0, stream>>>(partials, NBLK_MAIN, (float*)d_out);
}

// Round 6
// 105.844 us; speedup vs baseline: 1.0484x; 1.0193x over previous
//
#include <hip/hip_runtime.h>

// SampledSoftmaxLoss: N=51200 rows, D=64, K=100 negatives, V=100001 items.
// loss = sum_n w_n * (logsumexp(logits_n) - pos_logit_n) / sum_n w_n
// logits = cos_sim(vo_n, item_idx) / 0.05
//
// r12 = r11 with NT-builtin types fixed (ext_vector instead of HIP vector).
// r11: TWO-KERNEL D-SPLIT. Ledger:
//  r5  (1 table, wave-private, no barriers): 59.7us, FETCH 152MB @2.6TB/s
//      -> random-gather L2-miss path is the limiter (6.4MB table > 4MB L2).
//  r9  (D-split, block barriers): FETCH 68MB (gathers became cache hits ->
//      capacity theory CONFIRMED) but 104us: __syncthreads = vmcnt(0) drain
//      right after issuing next row's loads -> zero pipeline depth.
//  r10 (D-split, wave-private, 1 kernel): 103us, FETCH 181MB -> phases
//      drift without a hard boundary; both tables live -> thrash + 32B rows
//      waste half of each 64B line.
// Conclusion: phase separation needs a KERNEL BOUNDARY; pipelining needs
// NO BARRIERS. Kernel A: tabA (dims 0-31, 3.2MB, L2-resident chip-wide)
// -> 32-dim partial dots, packed fp16 (7 partials + ssA) into one uint4
// per (row,g), NT-stored to ws (13.1MB streaming). Kernel B: tabB hot,
// re-resolve indices (NT stream re-read), complete dots + softmax + loss.
// NT hints on all streams so they don't evict the resident table. fp16
// partial noise (~6e-3/logit) << fp8 table noise (~0.05) -> accuracy ok.

#define D_DIM 64
#define K_NEG 100
#define INV_TEMP 20.0f
#define MAX_LOGIT 20.0f
#define LOG2E 1.4426950408889634f
#define LN2 0.6931471805599453f
#define MAXL2 28.853900817779268f   // MAX_LOGIT * LOG2E

#define NBLK_MAIN 2048
#define NBLK_NORM 1024
#define NT 7      // ceil(101/16) tiles of 16 slots

typedef float fv2 __attribute__((ext_vector_type(2)));
typedef float fv4 __attribute__((ext_vector_type(4)));
typedef unsigned int uv2 __attribute__((ext_vector_type(2)));
typedef unsigned int uv4 __attribute__((ext_vector_type(4)));
typedef _Float16 hv2 __attribute__((ext_vector_type(2)));
union HU { hv2 h; unsigned int u; };

// ------- Pass 1: normalize item table -> fp8 e4m3, split by dims -------
// tabA[v] = dims 0-31 (32B, 8 dwords), tabB[v] = dims 32-63.
__global__ __launch_bounds__(256) void normalize_kernel(
    const float* __restrict__ items, unsigned int* __restrict__ tabA,
    unsigned int* __restrict__ tabB, int V) {
  const int lane = threadIdx.x & 63;
  const int wid  = threadIdx.x >> 6;
  const int g = lane >> 4, q = lane & 15;   // q covers dims 4q..4q+3
  const int waveId = blockIdx.x * 4 + wid;
  const int nWaves = gridDim.x * 4;
  for (int base = waveId * 4; base < V; base += nWaves * 4) {
    const int r = base + g;
    const bool act = (r < V);
    fv4 x = {0.f, 0.f, 0.f, 0.f};
    if (act) x = *reinterpret_cast<const fv4*>(items + (size_t)r * D_DIM + q * 4);
    float ss = x.x * x.x + x.y * x.y + x.z * x.z + x.w * x.w;
    ss += __shfl_xor(ss, 1);
    ss += __shfl_xor(ss, 2);
    ss += __shfl_xor(ss, 4);
    ss += __shfl_xor(ss, 8);
    const float inv = 1.0f / fmaxf(sqrtf(ss), 1e-12f);
    if (act) {
      int u = 0;
      u = __builtin_amdgcn_cvt_pk_fp8_f32(x.x * inv, x.y * inv, u, false);
      u = __builtin_amdgcn_cvt_pk_fp8_f32(x.z * inv, x.w * inv, u, true);
      unsigned int* t = (q < 8) ? (tabA + (size_t)r * 8 + q)
                                : (tabB + (size_t)r * 8 + (q - 8));
      *t = (unsigned int)u;
    }
  }
}

// Shared per-wave helpers (16 groups x 4 lanes; group g owns slot j=16t+g,
// lane q owns 8 dims of the active 32-dim window).
#define LOADN_BODY(row, nj)                                                  \
  {                                                                          \
    const int* nr = negi + (size_t)(row)*K_NEG;                              \
    nj[0] = (g >= 1) ? __builtin_nontemporal_load(nr + g - 1) : 0;           \
    nj[1] = __builtin_nontemporal_load(nr + 16 + g - 1);                     \
    nj[2] = __builtin_nontemporal_load(nr + 32 + g - 1);                     \
    nj[3] = __builtin_nontemporal_load(nr + 48 + g - 1);                     \
    nj[4] = __builtin_nontemporal_load(nr + 64 + g - 1);                     \
    nj[5] = __builtin_nontemporal_load(nr + 80 + g - 1);                     \
    nj[6] = (g <= 4) ? __builtin_nontemporal_load(nr + 96 + g - 1) : 0;      \
  }

#define RESOLVE_BODY(nj, t_r, row, id)                                       \
  {                                                                          \
    const int* ar = alti + (size_t)(row)*K_NEG;                              \
    int v0 = (g == 0) ? (t_r) : nj[0];                                       \
    if (g >= 1 && v0 == (t_r)) v0 = ar[g - 1];                               \
    id[0] = v0;                                                              \
    int v1 = nj[1]; if (v1 == (t_r)) v1 = ar[16 + g - 1]; id[1] = v1;        \
    int v2 = nj[2]; if (v2 == (t_r)) v2 = ar[32 + g - 1]; id[2] = v2;        \
    int v3 = nj[3]; if (v3 == (t_r)) v3 = ar[48 + g - 1]; id[3] = v3;        \
    int v4 = nj[4]; if (v4 == (t_r)) v4 = ar[64 + g - 1]; id[4] = v4;        \
    int v5 = nj[5]; if (v5 == (t_r)) v5 = ar[80 + g - 1]; id[5] = v5;        \
    int v6 = 0;                                                              \
    if (g <= 4) { v6 = nj[6]; if (v6 == (t_r)) v6 = ar[96 + g - 1]; }        \
    id[6] = v6;                                                              \
  }

// ------- Pass 2a: partial dots over dims 0-31 (tabA L2-resident) -------
__global__ __launch_bounds__(256) void partial_kernel(
    const float* __restrict__ oe,          // [N,64]
    const int*   __restrict__ tgt,         // [N]
    const unsigned int* __restrict__ tabA, // [V][8] dwords fp8 (dims 0-31)
    const int*   __restrict__ negi,        // [N,100]
    const int*   __restrict__ alti,        // [N,100]
    unsigned int* __restrict__ part,       // [N][64] dwords: packed fp16
    int N) {
  const int lane = threadIdx.x & 63;
  const int g = lane >> 2, q = lane & 3;
  const int waveId = blockIdx.x * 4 + (threadIdx.x >> 6);
  const int nWaves = gridDim.x * 4;

  int row = waveId;
  int t_r = 0, nj[NT];
  fv4 a0 = {0.f, 0.f, 0.f, 0.f}, a1 = a0;
  if (row < N) {
    t_r = tgt[row];
    LOADN_BODY(row, nj);
    const float* orow = oe + (size_t)row * D_DIM + q * 8;   // dims q*8..q*8+7
    a0 = __builtin_nontemporal_load(reinterpret_cast<const fv4*>(orow));
    a1 = __builtin_nontemporal_load(reinterpret_cast<const fv4*>(orow) + 1);
  }

  while (row < N) {
    const int nxt = row + nWaves;
    int id[NT];
    RESOLVE_BODY(nj, t_r, row, id);
    uv2 rb[NT];
#pragma unroll
    for (int t = 0; t < NT; ++t)
      rb[t] = *reinterpret_cast<const uv2*>(tabA + (size_t)id[t] * 8 + q * 2);

    // prefetch next row's streams under the gather latency
    fv4 b0 = {0.f, 0.f, 0.f, 0.f}, b1 = b0;
    int p_t = 0;
    if (nxt < N) {
      p_t = tgt[nxt];
      LOADN_BODY(nxt, nj);   // nj dead for current row (already resolved)
      const float* prow = oe + (size_t)nxt * D_DIM + q * 8;
      b0 = __builtin_nontemporal_load(reinterpret_cast<const fv4*>(prow));
      b1 = __builtin_nontemporal_load(reinterpret_cast<const fv4*>(prow) + 1);
    }

    // compute: 32-dim |q|^2 partial + 7 partial dots
    const fv2 qa0 = {a0.x, a0.y}, qa1 = {a0.z, a0.w};
    const fv2 qa2 = {a1.x, a1.y}, qa3 = {a1.z, a1.w};
    fv2 ss2 = qa0 * qa0;
    ss2 += qa1 * qa1;
    ss2 += qa2 * qa2;
    ss2 += qa3 * qa3;
    float ss = ss2[0] + ss2[1];
    ss += __shfl_xor(ss, 1);
    ss += __shfl_xor(ss, 2);      // quad sum = full 32-dim ssA (all lanes)

    float dv[NT];
#pragma unroll
    for (int t = 0; t < NT; ++t) {
      const uv2 r2 = rb[t];
      fv2 acc;
      acc  = qa0 * __builtin_amdgcn_cvt_pk_f32_fp8((int)r2.x, false);
      acc += qa1 * __builtin_amdgcn_cvt_pk_f32_fp8((int)r2.x, true);
      acc += qa2 * __builtin_amdgcn_cvt_pk_f32_fp8((int)r2.y, false);
      acc += qa3 * __builtin_amdgcn_cvt_pk_f32_fp8((int)r2.y, true);
      float d = acc[0] + acc[1];
      d += __shfl_xor(d, 1);
      d += __shfl_xor(d, 2);      // slot-j 32-dim partial (uniform in quad)
      dv[t] = d;
    }

    // pack 7 partials + ssA as 8 halves -> one uv4 per (row, g)
    HU u0, u1, u2, u3;
    u0.h = hv2{(_Float16)dv[0], (_Float16)dv[1]};
    u1.h = hv2{(_Float16)dv[2], (_Float16)dv[3]};
    u2.h = hv2{(_Float16)dv[4], (_Float16)dv[5]};
    u3.h = hv2{(_Float16)dv[6], (_Float16)ss};
    if (q == 0) {
      const uv4 pv = {u0.u, u1.u, u2.u, u3.u};
      __builtin_nontemporal_store(
          pv, reinterpret_cast<uv4*>(part + (size_t)row * 64 + g * 4));
    }

    a0 = b0; a1 = b1; t_r = p_t;
    row = nxt;
  }
}

// ------- Pass 2b: complete dots over dims 32-63 (tabB L2-resident) -------
__global__ __launch_bounds__(256) void loss_kernel(
    const float* __restrict__ oe,          // [N,64]
    const int*   __restrict__ tgt,         // [N]
    const unsigned int* __restrict__ tabB, // [V][8] dwords fp8 (dims 32-63)
    const float* __restrict__ wgt,         // [N]
    const int*   __restrict__ negi,        // [N,100]
    const int*   __restrict__ alti,        // [N,100]
    const unsigned int* __restrict__ part, // [N][64] dwords: packed fp16
    float2*      __restrict__ partials,    // [gridDim.x]
    int N) {
  __shared__ float2 s_red[4];
  const int lane = threadIdx.x & 63;
  const int wid  = threadIdx.x >> 6;
  const int g = lane >> 2, q = lane & 3;
  const int waveId = blockIdx.x * 4 + wid;
  const int nWaves = gridDim.x * 4;

  float num = 0.f, den = 0.f;

  int row = waveId;
  int t_r = 0, nj[NT];
  float w = 0.f;
  fv4 a0 = {0.f, 0.f, 0.f, 0.f}, a1 = a0;
  if (row < N) {
    t_r = tgt[row];
    w = wgt[row];
    LOADN_BODY(row, nj);
    const float* orow = oe + (size_t)row * D_DIM + 32 + q * 8;  // upper dims
    a0 = __builtin_nontemporal_load(reinterpret_cast<const fv4*>(orow));
    a1 = __builtin_nontemporal_load(reinterpret_cast<const fv4*>(orow) + 1);
  }

  while (row < N) {
    const int nxt = row + nWaves;
    int id[NT];
    RESOLVE_BODY(nj, t_r, row, id);
    uv2 rb[NT];
#pragma unroll
    for (int t = 0; t < NT; ++t)
      rb[t] = *reinterpret_cast<const uv2*>(tabB + (size_t)id[t] * 8 + q * 2);
    uv4 pu = {0u, 0u, 0u, 0u};
    if (q == 0)
      pu = __builtin_nontemporal_load(
          reinterpret_cast<const uv4*>(part + (size_t)row * 64 + g * 4));

    // prefetch next row's streams under the gather latency
    fv4 b0 = {0.f, 0.f, 0.f, 0.f}, b1 = b0;
    int p_t = 0;
    float p_w = 0.f;
    if (nxt < N) {
      p_t = tgt[nxt];
      p_w = wgt[nxt];
      LOADN_BODY(nxt, nj);
      const float* prow = oe + (size_t)nxt * D_DIM + 32 + q * 8;
      b0 = __builtin_nontemporal_load(reinterpret_cast<const fv4*>(prow));
      b1 = __builtin_nontemporal_load(reinterpret_cast<const fv4*>(prow) + 1);
    }

    // compute: upper-half |q|^2, then complete dots + softmax
    const fv2 qa0 = {a0.x, a0.y}, qa1 = {a0.z, a0.w};
    const fv2 qa2 = {a1.x, a1.y}, qa3 = {a1.z, a1.w};
    fv2 ss2 = qa0 * qa0;
    ss2 += qa1 * qa1;
    ss2 += qa2 * qa2;
    ss2 += qa3 * qa3;
    float ss = ss2[0] + ss2[1];
    ss += __shfl_xor(ss, 1);
    ss += __shfl_xor(ss, 2);

    HU u0, u1, u2, u3;
    u0.u = pu.x; u1.u = pu.y; u2.u = pu.z; u3.u = pu.w;
    const float ssA = __shfl((float)u3.h[1], 0);   // lane 0 holds real ssA
    const float sstot = ss + ssA;
    const float scale = INV_TEMP / fmaxf(sqrtf(sstot), 1e-12f);
    const float sc2 = scale * LOG2E;
    const float dvp[NT] = {(float)u0.h[0], (float)u0.h[1], (float)u1.h[0],
                           (float)u1.h[1], (float)u2.h[0], (float)u2.h[1],
                           (float)u3.h[0]};

    float sacc = 0.f, pos = 0.f;
#pragma unroll
    for (int t = 0; t < NT; ++t) {
      const uv2 r2 = rb[t];
      fv2 acc;
      acc  = qa0 * __builtin_amdgcn_cvt_pk_f32_fp8((int)r2.x, false);
      acc += qa1 * __builtin_amdgcn_cvt_pk_f32_fp8((int)r2.x, true);
      acc += qa2 * __builtin_amdgcn_cvt_pk_f32_fp8((int)r2.y, false);
      acc += qa3 * __builtin_amdgcn_cvt_pk_f32_fp8((int)r2.y, true);
      float d = acc[0] + acc[1];
      d += __shfl_xor(d, 1);
      d += __shfl_xor(d, 2);
      const int j = t * 16 + g;
      if (q == 0 && j <= K_NEG) {
        const float tot = d + dvp[t];
        sacc += exp2f(fmaf(tot, sc2, -MAXL2));
        if (j == 0) pos = tot * scale;   // lane 0 only (g=0,q=0,t=0)
      }
    }
    sacc += __shfl_xor(sacc, 4);
    sacc += __shfl_xor(sacc, 8);
    sacc += __shfl_xor(sacc, 16);
    sacc += __shfl_xor(sacc, 32);
    if (lane == 0) {
      const float lse = log2f(sacc) * LN2 + MAX_LOGIT;
      const float loss = lse - pos;
      if (w > 0.f) {
        num += loss * w;
        den += w;
      }
    }

    a0 = b0; a1 = b1; t_r = p_t; w = p_w;
    row = nxt;
  }

  if (lane == 0) s_red[wid] = make_float2(num, den);
  __syncthreads();
  if (threadIdx.x == 0) {
    float n = 0.f, d = 0.f;
#pragma unroll
    for (int i = 0; i < 4; ++i) { n += s_red[i].x; d += s_red[i].y; }
    partials[blockIdx.x] = make_float2(n, d);
  }
}

// ---------------- Pass 3: final reduce ----------------
__global__ __launch_bounds__(256) void finish_kernel(
    const float2* __restrict__ partials, int nblk, float* __restrict__ out) {
  float num = 0.f, den = 0.f;
  for (int i = threadIdx.x; i < nblk; i += 256) {
    const float2 p = partials[i];
    num += p.x;
    den += p.y;
  }
#pragma unroll
  for (int m = 1; m < 64; m <<= 1) {
    num += __shfl_xor(num, m);
    den += __shfl_xor(den, m);
  }
  __shared__ float2 red[4];
  const int wid = threadIdx.x >> 6;
  const int lane = threadIdx.x & 63;
  if (lane == 0) red[wid] = make_float2(num, den);
  __syncthreads();
  if (threadIdx.x == 0) {
    float n = 0.f, d = 0.f;
#pragma unroll
    for (int i = 0; i < 4; ++i) { n += red[i].x; d += red[i].y; }
    out[0] = n / d;
  }
}

extern "C" void kernel_launch(void* const* d_in, const int* in_sizes, int n_in,
                              void* d_out, int out_size, void* d_ws, size_t ws_size,
                              hipStream_t stream) {
  const float* oe    = (const float*)d_in[0];  // output_embeddings [B,S,64]
  const int*   tgt   = (const int*)  d_in[1];  // target_ids [B,S]
  const float* items = (const float*)d_in[2];  // all_item_embeddings [V,64]
  const float* wgt   = (const float*)d_in[3];  // supervision_weights [B,S]
  const int*   negi  = (const int*)  d_in[4];  // neg_indices [N,100]
  const int*   alti  = (const int*)  d_in[5];  // alt_neg_indices [N,100]

  const int N = in_sizes[0] / D_DIM;  // 51200
  const int V = in_sizes[2] / D_DIM;  // 100001

  unsigned int* tabA = (unsigned int*)d_ws;        // V*32 B (dims 0-31)
  unsigned int* tabB = tabA + (size_t)V * 8;       // V*32 B (dims 32-63)
  size_t off = ((size_t)V * 16 * sizeof(unsigned int) + 255) & ~(size_t)255;
  unsigned int* part = (unsigned int*)((char*)d_ws + off);  // N*256 B
  size_t off2 = (off + (size_t)N * 256 + 255) & ~(size_t)255;
  float2* partials = (float2*)((char*)d_ws + off2);

  normalize_kernel<<<NBLK_NORM, 256, 0, stream>>>(items, tabA, tabB, V);
  partial_kernel<<<NBLK_MAIN, 256, 0, stream>>>(oe, tgt, tabA, negi, alti,
                                                part, N);
  loss_kernel<<<NBLK_MAIN, 256, 0, stream>>>(oe, tgt, tabB, wgt, negi, alti,
                                             part, partials, N);
  finish_kernel<<<1, 256, 0, stream>>>(partials, NBLK_MAIN, (float*)d_out);
}

// Round 7
// 72.725 us; speedup vs baseline: 1.5259x; 1.4554x over previous
//
#include <hip/hip_runtime.h>

// SampledSoftmaxLoss: N=51200 rows, D=64, K=100 negatives, V=100001 items.
// loss = sum_n w_n * (logsumexp(logits_n) - pos_logit_n) / sum_n w_n
// logits = cos_sim(vo_n, item_idx) / 0.05
//
// r13: INT8 SDOT4, LANE-OWNS-SLOT, single pass. Ledger:
//  r5  59.7us: FETCH 152MB @2.6TB/s (fp8 table 6.4MB > 4MB L2).
//  r9/r12: D-split -> gathers become cache hits (FETCH=streams only,
//      capacity theory CONFIRMED) but each half-pass still costs 52us at
//      0.68TB/s, VALU 44% -> the STRUCTURE (idx resolve, per-tile shfl
//      chains, softmax, loop) is the floor, duplicated 2x. r5's 59.7 may
//      be the same floor, not the fetch wall.
// This round: keep ONE pass (overhead paid once), slash its cost:
//  - table + queries quantized to int8 (|err| < fp8's); queries
//    pre-normalized so per-row scale is one global constant 20/127^2.
//  - lane owns a whole slot: slot0=lane (0=pos), slot1=64+lane (<=100).
//    Full 64-dim dot in-lane via 16 v_dot4_i32_i8 -> ZERO per-tile
//    bpermutes (was 14/row); one 6-step wave reduce per row.
//  - 8 gather loads + 4 q8 loads per lane per row, idx prefetched a row
//    ahead (r5's proven barrier-free pipeline).
// Decisive A/B: FETCH returns to ~150MB. If dur ~60us w/ low VALU -> the
// 2.5TB/s L2-miss wall is real -> port this structure to two-pass D-split.
// If dur 40-50us -> r5 was structure-bound and this is the win.

#define D_DIM 64
#define K_NEG 100
#define INV_TEMP 20.0f
#define MAX_LOGIT 20.0f
#define LOG2E 1.4426950408889634f
#define LN2 0.6931471805599453f
#define MAXL2 28.853900817779268f        // MAX_LOGIT * LOG2E
#define MCONST (INV_TEMP / (127.0f * 127.0f))   // logit = dot_int * MCONST
#define MC2 (MCONST * LOG2E)

#define NBLK_MAIN 2048
#define NBLK_QNT 1024

typedef float fv4 __attribute__((ext_vector_type(4)));
typedef unsigned int uv4 __attribute__((ext_vector_type(4)));

__device__ __forceinline__ int DOT4(int a, int b, int c) {
#if __has_builtin(__builtin_amdgcn_sdot4)
  return __builtin_amdgcn_sdot4(a, b, c, false);
#else
  int r = c;
#pragma unroll
  for (int i = 0; i < 4; ++i)
    r += (int)(signed char)(a >> (8 * i)) * (int)(signed char)(b >> (8 * i));
  return r;
#endif
}

__device__ __forceinline__ unsigned int pack8(const fv4 x, float s) {
  const int b0 = (int)rintf(x.x * s) & 255;
  const int b1 = (int)rintf(x.y * s) & 255;
  const int b2 = (int)rintf(x.z * s) & 255;
  const int b3 = (int)rintf(x.w * s) & 255;
  return (unsigned)b0 | ((unsigned)b1 << 8) | ((unsigned)b2 << 16) |
         ((unsigned)b3 << 24);
}

// ---- Pass 1: l2-normalize + int8-quantize items AND queries ----
// wave handles 4 rows x 16 lanes x 4 dims; one packed dword per lane.
__global__ __launch_bounds__(256) void quantize_kernel(
    const float* __restrict__ items, unsigned int* __restrict__ tab8, int V,
    const float* __restrict__ oe, unsigned int* __restrict__ q8, int N) {
  const int lane = threadIdx.x & 63;
  const int wid  = threadIdx.x >> 6;
  const int g = lane >> 4, q = lane & 15;
  const int waveId = blockIdx.x * 4 + wid;
  const int nWaves = gridDim.x * 4;
  for (int base = waveId * 4; base < V; base += nWaves * 4) {
    const int r = base + g;
    const bool act = (r < V);
    fv4 x = {0.f, 0.f, 0.f, 0.f};
    if (act) x = *reinterpret_cast<const fv4*>(items + (size_t)r * D_DIM + q * 4);
    float ss = x.x * x.x + x.y * x.y + x.z * x.z + x.w * x.w;
    ss += __shfl_xor(ss, 1);
    ss += __shfl_xor(ss, 2);
    ss += __shfl_xor(ss, 4);
    ss += __shfl_xor(ss, 8);
    const float s = 127.0f / fmaxf(sqrtf(ss), 1e-12f);
    if (act) tab8[(size_t)r * 16 + q] = pack8(x, s);
  }
  for (int base = waveId * 4; base < N; base += nWaves * 4) {
    const int r = base + g;
    const bool act = (r < N);
    fv4 x = {0.f, 0.f, 0.f, 0.f};
    if (act) x = *reinterpret_cast<const fv4*>(oe + (size_t)r * D_DIM + q * 4);
    float ss = x.x * x.x + x.y * x.y + x.z * x.z + x.w * x.w;
    ss += __shfl_xor(ss, 1);
    ss += __shfl_xor(ss, 2);
    ss += __shfl_xor(ss, 4);
    ss += __shfl_xor(ss, 8);
    const float s = 127.0f / fmaxf(sqrtf(ss), 1e-12f);
    if (act) q8[(size_t)r * 16 + q] = pack8(x, s);
  }
}

// ---- Pass 2: main loss. One wave per row; lane owns slot lane and
// slot 64+lane (if <=100). Full 64-dim int8 dot in-lane (16 sdot4). ----
__global__ __launch_bounds__(256) void loss_kernel(
    const unsigned int* __restrict__ q8,   // [N][16] dwords int8 (normalized)
    const int*   __restrict__ tgt,         // [N]
    const unsigned int* __restrict__ tab8, // [V][16] dwords int8 (normalized)
    const float* __restrict__ wgt,         // [N]
    const int*   __restrict__ negi,        // [N,100]
    const int*   __restrict__ alti,        // [N,100]
    float2*      __restrict__ partials,    // [gridDim.x]
    int N) {
  __shared__ float2 s_red[4];
  const int lane = threadIdx.x & 63;
  const int wid  = threadIdx.x >> 6;
  const int waveId = blockIdx.x * 4 + wid;
  const int nWaves = gridDim.x * 4;
  const bool v1ok = (lane <= K_NEG - 64);  // slot1 = 64+lane valid (lane<=36)

  float num = 0.f, den = 0.f;

  int row = waveId;
  int t_r = 0, n0 = 0, n1 = 0;
  float w = 0.f;
  if (row < N) {
    t_r = tgt[row];
    w = wgt[row];
    const int* nr = negi + (size_t)row * K_NEG;
    if (lane >= 1) n0 = nr[lane - 1];
    if (v1ok) n1 = nr[63 + lane];
  }

  while (row < N) {
    const int nxt = row + nWaves;

    // resolve collisions (alt loaded only on rare collision, execz-skipped)
    const int* ar = alti + (size_t)row * K_NEG;
    int i0 = (lane == 0) ? t_r : n0;
    if (lane >= 1 && i0 == t_r) i0 = ar[lane - 1];
    int i1 = v1ok ? n1 : 0;
    if (v1ok && i1 == t_r) i1 = ar[63 + lane];

    // issue 8 gather loads (two random 64B item rows) + 4 q8 loads
    const uv4* t0 = reinterpret_cast<const uv4*>(tab8 + ((unsigned)i0 << 4));
    const uv4* t1 = reinterpret_cast<const uv4*>(tab8 + ((unsigned)i1 << 4));
    const uv4 a0 = t0[0], a1 = t0[1], a2 = t0[2], a3 = t0[3];
    const uv4 b0 = t1[0], b1 = t1[1], b2 = t1[2], b3 = t1[3];
    const uv4* qp = reinterpret_cast<const uv4*>(q8 + (size_t)row * 16);
    const uv4 q0 = qp[0], q1 = qp[1], q2 = qp[2], q3 = qp[3];

    // prefetch next row's index/scalar streams under the gather latency
    int p_t = 0, pn0 = 0, pn1 = 0;
    float p_w = 0.f;
    if (nxt < N) {
      p_t = tgt[nxt];
      p_w = wgt[nxt];
      const int* nr = negi + (size_t)nxt * K_NEG;
      if (lane >= 1) pn0 = __builtin_nontemporal_load(nr + lane - 1);
      if (v1ok) pn1 = __builtin_nontemporal_load(nr + 63 + lane);
    }

    // two full 64-dim int8 dots, fully in-lane (2 independent sdot4 chains)
    int d0 = 0, d1 = 0;
    d0 = DOT4((int)a0.x, (int)q0.x, d0);
    d1 = DOT4((int)b0.x, (int)q0.x, d1);
    d0 = DOT4((int)a0.y, (int)q0.y, d0);
    d1 = DOT4((int)b0.y, (int)q0.y, d1);
    d0 = DOT4((int)a0.z, (int)q0.z, d0);
    d1 = DOT4((int)b0.z, (int)q0.z, d1);
    d0 = DOT4((int)a0.w, (int)q0.w, d0);
    d1 = DOT4((int)b0.w, (int)q0.w, d1);
    d0 = DOT4((int)a1.x, (int)q1.x, d0);
    d1 = DOT4((int)b1.x, (int)q1.x, d1);
    d0 = DOT4((int)a1.y, (int)q1.y, d0);
    d1 = DOT4((int)b1.y, (int)q1.y, d1);
    d0 = DOT4((int)a1.z, (int)q1.z, d0);
    d1 = DOT4((int)b1.z, (int)q1.z, d1);
    d0 = DOT4((int)a1.w, (int)q1.w, d0);
    d1 = DOT4((int)b1.w, (int)q1.w, d1);
    d0 = DOT4((int)a2.x, (int)q2.x, d0);
    d1 = DOT4((int)b2.x, (int)q2.x, d1);
    d0 = DOT4((int)a2.y, (int)q2.y, d0);
    d1 = DOT4((int)b2.y, (int)q2.y, d1);
    d0 = DOT4((int)a2.z, (int)q2.z, d0);
    d1 = DOT4((int)b2.z, (int)q2.z, d1);
    d0 = DOT4((int)a2.w, (int)q2.w, d0);
    d1 = DOT4((int)b2.w, (int)q2.w, d1);
    d0 = DOT4((int)a3.x, (int)q3.x, d0);
    d1 = DOT4((int)b3.x, (int)q3.x, d1);
    d0 = DOT4((int)a3.y, (int)q3.y, d0);
    d1 = DOT4((int)b3.y, (int)q3.y, d1);
    d0 = DOT4((int)a3.z, (int)q3.z, d0);
    d1 = DOT4((int)b3.z, (int)q3.z, d1);
    d0 = DOT4((int)a3.w, (int)q3.w, d0);
    d1 = DOT4((int)b3.w, (int)q3.w, d1);

    // slot exps; slot0 always valid (j=lane<=63), slot1 masked
    float e = exp2f(fmaf((float)d0, MC2, -MAXL2));
    if (v1ok) e += exp2f(fmaf((float)d1, MC2, -MAXL2));

    // one wave reduce per row
    e += __shfl_xor(e, 1);
    e += __shfl_xor(e, 2);
    e += __shfl_xor(e, 4);
    e += __shfl_xor(e, 8);
    e += __shfl_xor(e, 16);
    e += __shfl_xor(e, 32);
    if (lane == 0) {
      const float pos = (float)d0 * MCONST;      // lane0 slot0 = positive
      const float lse = log2f(e) * LN2 + MAX_LOGIT;
      const float loss = lse - pos;
      if (w > 0.f) {
        num += loss * w;
        den += w;
      }
    }

    t_r = p_t; n0 = pn0; n1 = pn1; w = p_w;
    row = nxt;
  }

  if (lane == 0) s_red[wid] = make_float2(num, den);
  __syncthreads();
  if (threadIdx.x == 0) {
    float n = 0.f, d = 0.f;
#pragma unroll
    for (int i = 0; i < 4; ++i) { n += s_red[i].x; d += s_red[i].y; }
    partials[blockIdx.x] = make_float2(n, d);
  }
}

// ---------------- Pass 3: final reduce ----------------
__global__ __launch_bounds__(256) void finish_kernel(
    const float2* __restrict__ partials, int nblk, float* __restrict__ out) {
  float num = 0.f, den = 0.f;
  for (int i = threadIdx.x; i < nblk; i += 256) {
    const float2 p = partials[i];
    num += p.x;
    den += p.y;
  }
#pragma unroll
  for (int m = 1; m < 64; m <<= 1) {
    num += __shfl_xor(num, m);
    den += __shfl_xor(den, m);
  }
  __shared__ float2 red[4];
  const int wid = threadIdx.x >> 6;
  const int lane = threadIdx.x & 63;
  if (lane == 0) red[wid] = make_float2(num, den);
  __syncthreads();
  if (threadIdx.x == 0) {
    float n = 0.f, d = 0.f;
#pragma unroll
    for (int i = 0; i < 4; ++i) { n += red[i].x; d += red[i].y; }
    out[0] = n / d;
  }
}

extern "C" void kernel_launch(void* const* d_in, const int* in_sizes, int n_in,
                              void* d_out, int out_size, void* d_ws, size_t ws_size,
                              hipStream_t stream) {
  const float* oe    = (const float*)d_in[0];  // output_embeddings [B,S,64]
  const int*   tgt   = (const int*)  d_in[1];  // target_ids [B,S]
  const float* items = (const float*)d_in[2];  // all_item_embeddings [V,64]
  const float* wgt   = (const float*)d_in[3];  // supervision_weights [B,S]
  const int*   negi  = (const int*)  d_in[4];  // neg_indices [N,100]
  const int*   alti  = (const int*)  d_in[5];  // alt_neg_indices [N,100]

  const int N = in_sizes[0] / D_DIM;  // 51200
  const int V = in_sizes[2] / D_DIM;  // 100001

  unsigned int* tab8 = (unsigned int*)d_ws;          // V*64 B int8 table
  size_t off = ((size_t)V * 64 + 255) & ~(size_t)255;
  unsigned int* q8 = (unsigned int*)((char*)d_ws + off);  // N*64 B int8 queries
  size_t off2 = (off + (size_t)N * 64 + 255) & ~(size_t)255;
  float2* partials = (float2*)((char*)d_ws + off2);       // NBLK_MAIN float2

  quantize_kernel<<<NBLK_QNT, 256, 0, stream>>>(items, tab8, V, oe, q8, N);
  loss_kernel<<<NBLK_MAIN, 256, 0, stream>>>(q8, tgt, tab8, wgt, negi, alti,
                                             partials, N);
  finish_kernel<<<1, 256, 0, stream>>>(partials, NBLK_MAIN, (float*)d_out);
}